// Round 12
// baseline (476.325 us; speedup 1.0000x reference)
//
#include <hip/hip_runtime.h>
#include <stdint.h>

#define BSH 7           // fine bucket shift: 128 cols per bucket
#define BW  128         // fine bucket width
#define MAXBUK 2048     // >= ceil(250000/128) = 1954
#define SSH 13          // superbucket shift: 8192 cols
#define SBW 8192
#define MAXSB 64        // >= 31 superbuckets
#define CMAX 4096       // LDS edge-cache per binning block

// ---------------- fine histogram (col >> BSH) ----------------
__global__ void k_hist(const int* __restrict__ ei, int E, int nbuk, int* __restrict__ bcnt) {
    __shared__ int h[MAXBUK];
    for (int b = threadIdx.x; b < nbuk; b += blockDim.x) h[b] = 0;
    __syncthreads();
    int stride = gridDim.x * blockDim.x;
    for (int e = blockIdx.x * blockDim.x + threadIdx.x; e < E; e += stride)
        atomicAdd(&h[ei[E + e] >> BSH], 1);
    __syncthreads();
    for (int b = threadIdx.x; b < nbuk; b += blockDim.x)
        if (h[b]) atomicAdd(&bcnt[b], h[b]);
}

// ---------------- exclusive scan of fine counts + superbucket bases ----------------
__global__ void k_scan(const int* __restrict__ bcnt, int nbuk, int E, int nsb,
                       int* __restrict__ bbase, int* __restrict__ cursor,
                       int* __restrict__ sbase, int* __restrict__ scursor) {
    __shared__ int s0[MAXBUK], s1[MAXBUK];
    int tid = threadIdx.x;
    for (int i = tid; i < MAXBUK; i += blockDim.x) s0[i] = (i < nbuk) ? bcnt[i] : 0;
    __syncthreads();
    int* src = s0; int* dst = s1;
    for (int off = 1; off < MAXBUK; off <<= 1) {
        for (int i = tid; i < MAXBUK; i += blockDim.x)
            dst[i] = src[i] + ((i >= off) ? src[i - off] : 0);
        __syncthreads();
        int* t = src; src = dst; dst = t;
    }
    // src[] holds the inclusive scan
    for (int i = tid; i < nbuk; i += blockDim.x) {
        int excl = src[i] - bcnt[i];
        bbase[i] = excl;
        cursor[i] = excl;
    }
    if (tid == 0) bbase[nbuk] = E;
    for (int i = tid; i <= nsb; i += blockDim.x) {
        int idx = i << 6;
        int v = (idx < nbuk) ? (src[idx] - bcnt[idx]) : E;
        sbase[i] = v;
        if (i < nsb) scursor[i] = v;
    }
}

// ---------------- pass 1: bin into 31 superbuckets ----------------
// tmp[pos] = (row << SSH) | (col & (SBW-1))
__global__ void k_bin1(const int* __restrict__ ei, int E,
                       int* __restrict__ scursor, unsigned int* __restrict__ tmp) {
    __shared__ int colc[CMAX];
    __shared__ int h[MAXSB], base[MAXSB];
    int start = (int)blockIdx.x * CMAX;
    int end = min(start + CMAX, E);
    int cnt = end - start;
    if (threadIdx.x < MAXSB) h[threadIdx.x] = 0;
    __syncthreads();
    for (int i = threadIdx.x; i < cnt; i += blockDim.x) {
        int c = ei[E + start + i];
        colc[i] = c;
        atomicAdd(&h[c >> SSH], 1);
    }
    __syncthreads();
    if (threadIdx.x < MAXSB) {
        int c = h[threadIdx.x];
        base[threadIdx.x] = c ? atomicAdd(&scursor[threadIdx.x], c) : 0;
        h[threadIdx.x] = 0;                     // reuse as local cursor
    }
    __syncthreads();
    for (int i = threadIdx.x; i < cnt; i += blockDim.x) {
        int r = ei[start + i];
        int c = colc[i];
        int sb = c >> SSH;
        int loc = atomicAdd(&h[sb], 1);
        tmp[base[sb] + loc] = ((unsigned)r << SSH) | (unsigned)(c & (SBW - 1));
    }
}

// ---------------- pass 2: refine each superbucket into 64 fine buckets ----------------
// pairs[pos] = (row << BSH) | (col & (BW-1)), grouped by fine bucket.
__global__ void k_bin2(const unsigned int* __restrict__ tmp, const int* __restrict__ sbase,
                       int* __restrict__ cursor, unsigned int* __restrict__ pairs) {
    __shared__ unsigned int cache[CMAX];
    __shared__ int h[64], base[64];
    int sb = blockIdx.x;
    int s = sbase[sb], e = sbase[sb + 1];
    int cnt = e - s;
    int chunk = (cnt + (int)gridDim.y - 1) / (int)gridDim.y;
    int start = s + (int)blockIdx.y * chunk;
    int end = min(start + chunk, e);
    int m = max(0, end - start);
    if (threadIdx.x < 64) h[threadIdx.x] = 0;
    __syncthreads();
    for (int i = threadIdx.x; i < m; i += blockDim.x) {
        unsigned v = tmp[start + i];
        cache[i] = v;
        atomicAdd(&h[(v & (SBW - 1u)) >> BSH], 1);
    }
    __syncthreads();
    if (threadIdx.x < 64) {
        int c = h[threadIdx.x];
        int fine = (sb << 6) + threadIdx.x;
        base[threadIdx.x] = c ? atomicAdd(&cursor[fine], c) : 0;
        h[threadIdx.x] = 0;                     // reuse as local cursor
    }
    __syncthreads();
    for (int i = threadIdx.x; i < m; i += blockDim.x) {
        unsigned v = cache[i];
        unsigned colLow = v & (SBW - 1u);
        int lb = (int)(colLow >> BSH);
        int loc = atomicAdd(&h[lb], 1);
        pairs[base[lb] + loc] = ((v >> SSH) << BSH) | (colLow & (BW - 1u));
    }
}

// ---------------- pass 3: per-bucket counting sort -> full CSR ----------------
// rows[] in column order; colptr[col]; dinv+s4 fused. Order of rows within a
// column is non-deterministic; consumers accumulate in f64 (order-insensitive).
__global__ void k_sort(const unsigned int* __restrict__ pairs, const int* __restrict__ bbase,
                       const float* __restrict__ x, const float* __restrict__ y1, int n, int E,
                       int* __restrict__ rows, int* __restrict__ colptr,
                       float* __restrict__ dinv, float4* __restrict__ s4) {
    __shared__ int cnt[BW];
    __shared__ int cbase[BW];
    int b = blockIdx.x;
    int s = bbase[b], e = bbase[b + 1];
    if (threadIdx.x < BW) cnt[threadIdx.x] = 0;
    __syncthreads();
    for (int j = s + threadIdx.x; j < e; j += blockDim.x)
        atomicAdd(&cnt[pairs[j] & (BW - 1u)], 1);
    __syncthreads();
    if (threadIdx.x < BW) cbase[threadIdx.x] = cnt[threadIdx.x];
    __syncthreads();
    for (int off = 1; off < BW; off <<= 1) {
        int v = 0;
        if (threadIdx.x < BW && threadIdx.x >= off) v = cbase[threadIdx.x - off];
        __syncthreads();
        if (threadIdx.x < BW) cbase[threadIdx.x] += v;
        __syncthreads();
    }
    if (threadIdx.x < BW) {
        int excl = cbase[threadIdx.x] - cnt[threadIdx.x];   // exclusive within bucket
        int col = (b << BSH) + threadIdx.x;
        if (col < n) {
            colptr[col] = s + excl;
            float d = rsqrtf((float)cnt[threadIdx.x] + 1.0f);
            dinv[col] = d;
            s4[col] = make_float4(d * x[2 * col], d * x[2 * col + 1], d * y1[col], d);
        }
        cnt[threadIdx.x] = excl;                // reuse as cursor
    }
    if (b == 0 && threadIdx.x == 0) colptr[n] = E;
    __syncthreads();
    for (int j = s + threadIdx.x; j < e; j += blockDim.x) {
        unsigned pk = pairs[j];
        int pos = atomicAdd(&cnt[pk & (BW - 1u)], 1);
        rows[s + pos] = (int)(pk >> BSH);
    }
}

// ---------------- fused layer 1 (CSR, no LDS): agg3 -> W1+ReLU -> W2*dinv ----------------
// group of 32 lanes per node; lanes stride edges; f64 butterfly reduce in registers
__global__ void k_L1(const int* __restrict__ rows, const int* __restrict__ colptr,
                     const float4* __restrict__ s4, const float* __restrict__ W1,
                     const float* __restrict__ b1, const float* __restrict__ W2,
                     float* __restrict__ hs2, int n) {
    int t = blockIdx.x * blockDim.x + threadIdx.x;
    int g = t >> 5, f = t & 31;
    if (g >= n) return;
    int s = colptr[g], e = colptr[g + 1];
    double a0 = 0.0, a1 = 0.0, a2 = 0.0;
    for (int j = s + f; j < e; j += 32) {
        float4 v = s4[rows[j]];
        a0 += (double)v.x; a1 += (double)v.y; a2 += (double)v.z;
    }
#pragma unroll
    for (int off = 16; off > 0; off >>= 1) {
        a0 += __shfl_xor(a0, off, 32);
        a1 += __shfl_xor(a1, off, 32);
        a2 += __shfl_xor(a2, off, 32);
    }
    float4 sc = s4[g];
    float A0 = (float)a0 + sc.x;                // + self loop
    float A1 = (float)a1 + sc.y;
    float A2 = (float)a2 + sc.z;
    float d = sc.w;
    float h1 = fmaxf(d * (A0 * W1[f] + A1 * W1[32 + f] + A2 * W1[64 + f]) + b1[f], 0.0f);
    float o = 0.0f;
#pragma unroll
    for (int k = 0; k < 32; ++k)
        o += __shfl(h1, k, 32) * W2[k * 32 + f];
    hs2[(size_t)g * 32 + f] = d * o;
}

// ---------------- fused layer 2 + W3 (CSR, no LDS): register f64 accumulation ----------------
__global__ void k_L2(const int* __restrict__ rows, const int* __restrict__ colptr,
                     const float* __restrict__ hs2, const float* __restrict__ dinv,
                     const float* __restrict__ b2, const float* __restrict__ W3,
                     float* __restrict__ hs3, int n) {
    int t = blockIdx.x * blockDim.x + threadIdx.x;
    int g = t >> 5, f = t & 31;
    if (g >= n) return;
    int s = colptr[g], e = colptr[g + 1];
    double acc = 0.0;
    int j = s;
    for (; j + 7 < e; j += 8) {                 // 8 gathers in flight per group
        int r0 = rows[j],     r1 = rows[j + 1], r2 = rows[j + 2], r3 = rows[j + 3];
        int r4 = rows[j + 4], r5 = rows[j + 5], r6 = rows[j + 6], r7 = rows[j + 7];
        float v0 = hs2[(size_t)r0 * 32 + f], v1 = hs2[(size_t)r1 * 32 + f];
        float v2 = hs2[(size_t)r2 * 32 + f], v3 = hs2[(size_t)r3 * 32 + f];
        float v4 = hs2[(size_t)r4 * 32 + f], v5 = hs2[(size_t)r5 * 32 + f];
        float v6 = hs2[(size_t)r6 * 32 + f], v7 = hs2[(size_t)r7 * 32 + f];
        acc += (((double)v0 + (double)v1) + ((double)v2 + (double)v3))
             + (((double)v4 + (double)v5) + ((double)v6 + (double)v7));
    }
    for (; j < e; ++j) acc += (double)hs2[(size_t)rows[j] * 32 + f];
    float d = dinv[g];
    float h2 = fmaxf(d * ((float)acc + hs2[(size_t)g * 32 + f]) + b2[f], 0.0f);
    float w = h2 * W3[f];
#pragma unroll
    for (int off = 16; off > 0; off >>= 1) w += __shfl_down(w, off, 32);
    if (f == 0) hs3[g] = d * w;
}

// ---------------- layer 3 aggregate (CSR, no LDS) ----------------
__global__ void k_L3(const int* __restrict__ rows, const int* __restrict__ colptr,
                     const float* __restrict__ hs3, const float* __restrict__ dinv,
                     const float* __restrict__ b3, float* __restrict__ out, int n) {
    int t = blockIdx.x * blockDim.x + threadIdx.x;
    int g = t >> 5, l = t & 31;
    if (g >= n) return;
    int s = colptr[g], e = colptr[g + 1];
    double acc = 0.0;
    for (int j = s + l; j < e; j += 32) acc += (double)hs3[rows[j]];
#pragma unroll
    for (int off = 16; off > 0; off >>= 1) acc += __shfl_down(acc, off, 32);
    if (l == 0) out[g] = dinv[g] * ((float)acc + hs3[g]) + b3[0];
}

// ---------------- launch ----------------

extern "C" void kernel_launch(void* const* d_in, const int* in_sizes, int n_in,
                              void* d_out, int out_size, void* d_ws, size_t ws_size,
                              hipStream_t stream) {
    const float* x  = (const float*)d_in[0];
    const float* y1 = (const float*)d_in[1];
    const int*   ei = (const int*)d_in[2];
    const float* W1 = (const float*)d_in[3];
    const float* b1 = (const float*)d_in[4];
    const float* W2 = (const float*)d_in[5];
    const float* b2 = (const float*)d_in[6];
    const float* W3 = (const float*)d_in[7];
    const float* b3 = (const float*)d_in[8];
    float* out = (float*)d_out;

    const int n = in_sizes[1];          // 250000
    const int E = in_sizes[2] / 2;      // 8000000
    const int nbuk = (n + BW - 1) >> BSH;   // 1954
    const int nsb = (nbuk + 63) >> 6;       // 31 superbuckets

    char* ws = (char*)d_ws;
    size_t off = 0;
    auto alloc = [&](size_t bytes) { char* p = ws + off; off += (bytes + 255) & ~(size_t)255; return p; };
    unsigned int* pairs = (unsigned int*)alloc((size_t)E * sizeof(unsigned int)); // 32MB
    int*    rows  = (int*)alloc((size_t)E * sizeof(int));                        // 32MB (aliases tmp)
    float*  hs2   = (float*)alloc((size_t)n * 32 * sizeof(float));               // 32MB
    float4* s4    = (float4*)alloc((size_t)n * sizeof(float4));                  // 4MB
    float*  dinv  = (float*)alloc((size_t)n * sizeof(float));
    float*  hs3   = (float*)alloc((size_t)n * sizeof(float));
    int*    colptr= (int*)alloc((size_t)(n + 1) * sizeof(int));
    int*    bcnt  = (int*)alloc((size_t)nbuk * sizeof(int));
    int*    bbase = (int*)alloc((size_t)(nbuk + 1) * sizeof(int));
    int*    cursor= (int*)alloc((size_t)nbuk * sizeof(int));
    int*    sbase = (int*)alloc((size_t)(nsb + 1) * sizeof(int));
    int*    scursor = (int*)alloc((size_t)nsb * sizeof(int));
    (void)ws_size;
    // tmp (pass-1 output) aliases rows: tmp is dead after k_bin2; k_sort then
    // overwrites the region with the final row array.
    unsigned int* tmp = (unsigned int*)rows;

    // fine histogram + scans
    hipMemsetAsync(bcnt, 0, (size_t)nbuk * sizeof(int), stream);
    k_hist<<<1024, 256, 0, stream>>>(ei, E, nbuk, bcnt);
    k_scan<<<1, 1024, 0, stream>>>(bcnt, nbuk, E, nsb, bbase, cursor, sbase, scursor);

    // three-pass radix partition -> full CSR
    const int nbin1 = (E + CMAX - 1) / CMAX;    // 1954 blocks
    k_bin1<<<nbin1, 256, 0, stream>>>(ei, E, scursor, tmp);
    k_bin2<<<dim3(nsb, 72), 256, 0, stream>>>(tmp, sbase, cursor, pairs);
    k_sort<<<nbuk, 256, 0, stream>>>(pairs, bbase, x, y1, n, E, rows, colptr, dinv, s4);

    // fused layers (all CSR, register f64 accumulation, no LDS atomics)
    const int gGrp = (n * 32 + 511) / 512;      // 15625 blocks of 512
    k_L1<<<gGrp, 512, 0, stream>>>(rows, colptr, s4, W1, b1, W2, hs2, n);
    k_L2<<<gGrp, 512, 0, stream>>>(rows, colptr, hs2, dinv, b2, W3, hs3, n);
    k_L3<<<gGrp, 512, 0, stream>>>(rows, colptr, hs3, dinv, b3, out, n);
}